// Round 17
// baseline (93.938 us; speedup 1.0000x reference)
//
#include <hip/hip_runtime.h>

#define LOG2E 1.44269504088896340736f

typedef _Float16 f16x8  __attribute__((ext_vector_type(8)));
typedef float    f32x4  __attribute__((ext_vector_type(4)));

template <int I> struct IntC { static constexpr int value = I; };
template <int I, int N, typename F>
__device__ __forceinline__ void sfor(F&& f) {
    if constexpr (I < N) { f(IntC<I>{}); sfor<I + 1, N>(f); }
}

__device__ __forceinline__ float fexp2(float x){ return __builtin_amdgcn_exp2f(x); }
__device__ __forceinline__ float frcp(float x){ return __builtin_amdgcn_rcpf(x); }

// fp16 pack: single v_cvt_pkrtz_f16_f32
__device__ __forceinline__ unsigned pkh(float a, float b){
    return __builtin_bit_cast(unsigned, __builtin_amdgcn_cvt_pkrtz(a, b));
}
__device__ __forceinline__ f16x8 mkBh(unsigned d0,unsigned d1,unsigned d2,unsigned d3){
    uint4 u{d0,d1,d2,d3};
    return __builtin_bit_cast(f16x8, u);
}

#define MFMA16H __builtin_amdgcn_mfma_f32_16x16x32_f16

// LSTM cell tail (r13-proven pair-batched form). dd[mt] holds SCALED
// preacts: i',f',o' = -log2e*pre, g' = 2log2e*pre.
//   sigma = 1/(1+exp2(-L*pre)) = 1/A;  tanh = (E-1)/(E+1)
// Gate rcp PAIR-batched (two independent chains — quad-batching serialized
// the critical path, +7us in r15); tanh(c) rcp quad-batched across rows.
__device__ __forceinline__ f32x4 cell_tail(const f32x4 (&dd)[4], f32x4& c){
    f32x4 Ei, Ef, Eg, Eo;
    sfor<0,4>([&](auto R){ constexpr int r=R.value;
        Ei[r] = fexp2(dd[0][r]);
        Ef[r] = fexp2(dd[1][r]);
        Eg[r] = fexp2(dd[2][r]);
        Eo[r] = fexp2(dd[3][r]);
    });
    f32x4 ov, cn;
    sfor<0,4>([&](auto R){ constexpr int r=R.value;
        float Ai = 1.f + Ei[r], Af = 1.f + Ef[r];
        float Ag = 1.f + Eg[r], Ao = 1.f + Eo[r];
        float p  = Ai*Af;  float rp = frcp(p);
        float iv = Af*rp;                 // sigma(i)
        float fv = Ai*rp;                 // sigma(f)
        float q2 = Ag*Ao;  float rq = frcp(q2);
        float gr = Ao*rq;                 // 1/Ag
        ov[r]    = Ag*rq;                 // sigma(o)
        float gv = (Eg[r]-1.f)*gr;        // tanh(g)
        cn[r] = fv*c[r] + iv*gv;
    });
    c = cn;
    f32x4 tc;
    sfor<0,4>([&](auto R){ constexpr int r=R.value;
        tc[r] = fexp2(cn[r]*(2.f*LOG2E));
    });
    float B0=tc[0]+1.f, B1=tc[1]+1.f, B2=tc[2]+1.f, B3=tc[3]+1.f;
    float P2=B0*B1, P3=P2*B2, P4=P3*B3;
    float r4=frcp(P4);
    float R3=P3*r4;
    float r3=B3*r4;
    float R2=P2*r3;
    float r2=B2*r3;
    float R1=B0*r2;
    float R0=B1*r2;
    f32x4 hv;
    hv[0] = ov[0]*((tc[0]-1.f)*R0);
    hv[1] = ov[1]*((tc[1]-1.f)*R1);
    hv[2] = ov[2]*((tc[2]-1.f)*R2);
    hv[3] = ov[3]*((tc[3]-1.f)*R3);
    return hv;
}

// One wave = 48 samples (3 groups of 16), ZERO LDS, all-fp16 MFMA.
// 3 groups (not 4): the problem has only B/64=4096 waves at 64/wave —
// grid-limited to 4 waves/SIMD (r16 lesson: occupancy can't rise via VGPR).
// 48/wave -> 5462 waves = 5.3/SIMD; VGPR target <=102 for 5 resident.
// Virtual-K: lane (q,sl) owns C/D rows 4q..4q+3 of sample sl; B element
// k=8q+e is that lane's own packed registers.
//   layer0 K: e<4 -> h0[4q+e]; e==4,5 -> x[2q],x[2q+1];
//             e==6 -> BIAS (A=bias0 on q==0 rows; B=1.0 on q==0); e==7 -> 0
//   layer1 K: e<4 -> h0[4q+e]; e>=4 -> h1[4q+e-4]  (bias1 in C)
//   FC     K: e<4 -> h1[4q+e]; else 0               (biasf in C)
__global__
__attribute__((amdgpu_flat_work_group_size(256,256)))
__attribute__((amdgpu_waves_per_eu(1,8)))
void lstm_mfma_kernel(const float* __restrict__ in,
                      const float* __restrict__ Wih0, const float* __restrict__ Whh0,
                      const float* __restrict__ bih0, const float* __restrict__ bhh0,
                      const float* __restrict__ Wih1, const float* __restrict__ Whh1,
                      const float* __restrict__ bih1, const float* __restrict__ bhh1,
                      const float* __restrict__ Wfc,  const float* __restrict__ bfc,
                      float* __restrict__ out, int B)
{
    const int lane = threadIdx.x & 63;
    const int wid  = threadIdx.x >> 6;
    const int q  = lane >> 4;       // k-group / row-group
    const int sl = lane & 15;       // sample slot (MFMA col)
    const long s0 = (long)(blockIdx.x*4 + wid)*48;

    // bias B-slot: 1.0 in element e=6 (low16 of word3) on q==0 lanes only
    const unsigned bslot = (q==0) ? 0x00003C00u : 0u;

    // ---- per-group validity (B%16==0 -> group all-valid or all-invalid) ----
    bool vg[3];
    const float* xb[3];
    sfor<0,3>([&](auto G){ constexpr int g=G.value;
        const long sg = s0 + g*16;
        vg[g] = sg < (long)B;
        const long sgc = vg[g] ? sg : 0;          // clamp: loads stay in-bounds
        xb[g] = in + (sgc + sl)*64 + 2*q;
    });

    // ---- weight A-frags (fp16 RTN, VGPR-resident), virtual-K layout,
    //      exp-scale folded per gate: mt==2 (g): +2*log2e, else -log2e.
    //      layer0 bias rides A-slot e==6 (q==0 rows) -> no bias0 registers.
    f16x8 a0[4], a1[4];
    f32x4 bias1[4];
    const f32x4 zc{0.f,0.f,0.f,0.f};
    sfor<0,4>([&](auto MT){ constexpr int mt = MT.value;
        constexpr float SC = (mt==2) ? (2.f*LOG2E) : (-LOG2E);
        const int gr = 16*mt + sl;                 // gate row (A row = sl)
        sfor<0,8>([&](auto E){ constexpr int e = E.value;
            float w0;
            if constexpr (e < 4)       w0 = Whh0[gr*16 + 4*q + e];
            else if constexpr (e < 6)  w0 = Wih0[gr*8 + 2*q + (e-4)];
            else if constexpr (e == 6) w0 = (q==0) ? (bih0[gr] + bhh0[gr]) : 0.f;
            else                       w0 = 0.f;
            a0[mt][e] = (_Float16)(w0 * SC);
            float w1;
            if constexpr (e < 4) w1 = Wih1[gr*16 + 4*q + e];
            else                 w1 = Whh1[gr*16 + 4*q + (e-4)];
            a1[mt][e] = (_Float16)(w1 * SC);
        });
        sfor<0,4>([&](auto R){ constexpr int r = R.value;
            const int gb = 16*mt + 4*q + r;        // C/D row = 4q+r
            bias1[mt][r] = (bih1[gb] + bhh1[gb]) * SC;
        });
    });

    // ---- state x3 groups: fp16-packed h + f32 cell, all lane-local ----
    unsigned P0h[3]={0,0,0}, Q0h[3]={0,0,0};
    unsigned P1h[3]={0,0,0}, Q1h[3]={0,0,0};
    f32x4 c0[3], c1[3];
    sfor<0,3>([&](auto G){ constexpr int g=G.value;
        c0[g] = f32x4{0,0,0,0}; c1[g] = f32x4{0,0,0,0};
    });

    // ---- x stream (r13 style: float2 carry, pack at top of layer 0) ----
    float2 xv[3];
    sfor<0,3>([&](auto G){ constexpr int g=G.value;
        xv[g] = *(const float2*)(xb[g]);
    });

#pragma unroll 2
    for (int t = 0; t < 8; ++t) {
        // prefetch next step's x (t==7: reload t=0, discarded — in bounds)
        const int nxt = (t==7) ? 0 : (t+1)*8;
        float2 xn[3];
        sfor<0,3>([&](auto G){ constexpr int g=G.value;
            xn[g] = *(const float2*)(xb[g] + nxt);
        });

        // ================= layer 0 (3 groups: independent chains) ==========
        sfor<0,3>([&](auto G){ constexpr int g=G.value;
            const unsigned xh = pkh(xv[g].x, xv[g].y);
            f16x8 Bh = mkBh(P0h[g], Q0h[g], xh, bslot);
            f32x4 dd[4];
            sfor<0,4>([&](auto MT){ constexpr int mt = MT.value;
                dd[mt] = MFMA16H(a0[mt], Bh, zc, 0,0,0);
            });
            f32x4 hv = cell_tail(dd, c0[g]);
            P0h[g] = pkh(hv[0],hv[1]);  Q0h[g] = pkh(hv[2],hv[3]);
        });

        // ================= layer 1 (3 groups) ==============================
        sfor<0,3>([&](auto G){ constexpr int g=G.value;
            f16x8 Bh = mkBh(P0h[g], Q0h[g], P1h[g], Q1h[g]);
            f32x4 dd[4];
            sfor<0,4>([&](auto MT){ constexpr int mt = MT.value;
                dd[mt] = MFMA16H(a1[mt], Bh, bias1[mt], 0,0,0);
            });
            f32x4 hv = cell_tail(dd, c1[g]);
            P1h[g] = pkh(hv[0],hv[1]);  Q1h[g] = pkh(hv[2],hv[3]);
        });

        sfor<0,3>([&](auto G){ constexpr int g=G.value; xv[g] = xn[g]; });
    }

    // ================= FC: single fp16 MFMA, biasf in C =====================
    {
        f16x8 af;
        f32x4 biasf;
        sfor<0,8>([&](auto E){ constexpr int e = E.value;
            float wf = 0.f;
            if constexpr (e < 4) { if (sl < 10) wf = Wfc[sl*16 + 4*q + e]; }
            af[e] = (_Float16)wf;
        });
        sfor<0,4>([&](auto R){ constexpr int r = R.value;
            const int gb = 4*q + r;
            biasf[r] = (gb < 10) ? bfc[gb] : 0.f;
        });
        sfor<0,3>([&](auto G){ constexpr int g=G.value;
            f16x8 Bh = mkBh(P1h[g], Q1h[g], 0u, 0u);
            f32x4 d = MFMA16H(af, Bh, biasf, 0,0,0);
            if (vg[g]) {
                float* orow = out + (s0 + g*16 + sl)*10;
                if (q == 0)      { *(float2*)(orow+0) = float2{d[0],d[1]}; *(float2*)(orow+2) = float2{d[2],d[3]}; }
                else if (q == 1) { *(float2*)(orow+4) = float2{d[0],d[1]}; *(float2*)(orow+6) = float2{d[2],d[3]}; }
                else if (q == 2) { *(float2*)(orow+8) = float2{d[0],d[1]}; }
            }
        });
    }
}

extern "C" void kernel_launch(void* const* d_in, const int* in_sizes, int n_in,
                              void* d_out, int out_size, void* d_ws, size_t ws_size,
                              hipStream_t stream) {
    const float* in   = (const float*)d_in[0];
    const float* Wih0 = (const float*)d_in[1];
    const float* Whh0 = (const float*)d_in[2];
    const float* bih0 = (const float*)d_in[3];
    const float* bhh0 = (const float*)d_in[4];
    const float* Wih1 = (const float*)d_in[5];
    const float* Whh1 = (const float*)d_in[6];
    const float* bih1 = (const float*)d_in[7];
    const float* bhh1 = (const float*)d_in[8];
    const float* Wfc  = (const float*)d_in[9];
    const float* bfc  = (const float*)d_in[10];
    float* out = (float*)d_out;

    int B = in_sizes[0] / 64;                         // 262144 samples
    int grid = (B + 192 - 1) / 192;                   // 48 samples/wave * 4 waves
    lstm_mfma_kernel<<<grid, 256, 0, stream>>>(in, Wih0, Whh0, bih0, bhh0,
                                               Wih1, Whh1, bih1, bhh1,
                                               Wfc, bfc, out, B);
}

// Round 18
// 92.704 us; speedup vs baseline: 1.0133x; 1.0133x over previous
//
#include <hip/hip_runtime.h>

#define LOG2E 1.44269504088896340736f

typedef _Float16 f16x8  __attribute__((ext_vector_type(8)));
typedef float    f32x4  __attribute__((ext_vector_type(4)));

template <int I> struct IntC { static constexpr int value = I; };
template <int I, int N, typename F>
__device__ __forceinline__ void sfor(F&& f) {
    if constexpr (I < N) { f(IntC<I>{}); sfor<I + 1, N>(f); }
}

__device__ __forceinline__ float fexp2(float x){ return __builtin_amdgcn_exp2f(x); }
__device__ __forceinline__ float frcp(float x){ return __builtin_amdgcn_rcpf(x); }

// fp16 pack: single v_cvt_pkrtz_f16_f32
__device__ __forceinline__ unsigned pkh(float a, float b){
    return __builtin_bit_cast(unsigned, __builtin_amdgcn_cvt_pkrtz(a, b));
}
__device__ __forceinline__ f16x8 mkBh(unsigned d0,unsigned d1,unsigned d2,unsigned d3){
    uint4 u{d0,d1,d2,d3};
    return __builtin_bit_cast(f16x8, u);
}

#define MFMA16H __builtin_amdgcn_mfma_f32_16x16x32_f16

// LSTM cell tail (r13-proven pair-batched form). dd[mt] holds SCALED
// preacts: i',f',o' = -log2e*pre, g' = 2log2e*pre.
// Gate rcp PAIR-batched (two independent chains/row — quad-batching
// serialized the path, +4-7us in r15); tanh(c) rcp quad-batched across rows.
__device__ __forceinline__ f32x4 cell_tail(const f32x4 (&dd)[4], f32x4& c){
    f32x4 Ei, Ef, Eg, Eo;
    sfor<0,4>([&](auto R){ constexpr int r=R.value;
        Ei[r] = fexp2(dd[0][r]);
        Ef[r] = fexp2(dd[1][r]);
        Eg[r] = fexp2(dd[2][r]);
        Eo[r] = fexp2(dd[3][r]);
    });
    f32x4 ov, cn;
    sfor<0,4>([&](auto R){ constexpr int r=R.value;
        float Ai = 1.f + Ei[r], Af = 1.f + Ef[r];
        float Ag = 1.f + Eg[r], Ao = 1.f + Eo[r];
        float p  = Ai*Af;  float rp = frcp(p);
        float iv = Af*rp;                 // sigma(i)
        float fv = Ai*rp;                 // sigma(f)
        float q2 = Ag*Ao;  float rq = frcp(q2);
        float gr = Ao*rq;                 // 1/Ag
        ov[r]    = Ag*rq;                 // sigma(o)
        float gv = (Eg[r]-1.f)*gr;        // tanh(g)
        cn[r] = fv*c[r] + iv*gv;
    });
    c = cn;
    f32x4 tc;
    sfor<0,4>([&](auto R){ constexpr int r=R.value;
        tc[r] = fexp2(cn[r]*(2.f*LOG2E));
    });
    float B0=tc[0]+1.f, B1=tc[1]+1.f, B2=tc[2]+1.f, B3=tc[3]+1.f;
    float P2=B0*B1, P3=P2*B2, P4=P3*B3;
    float r4=frcp(P4);
    float R3=P3*r4;
    float r3=B3*r4;
    float R2=P2*r3;
    float r2=B2*r3;
    float R1=B0*r2;
    float R0=B1*r2;
    f32x4 hv;
    hv[0] = ov[0]*((tc[0]-1.f)*R0);
    hv[1] = ov[1]*((tc[1]-1.f)*R1);
    hv[2] = ov[2]*((tc[2]-1.f)*R2);
    hv[3] = ov[3]*((tc[3]-1.f)*R3);
    return hv;
}

// One wave = 64 samples (4 groups of 16), ZERO LDS, all-fp16 MFMA.
// SOFTWARE-PIPELINED LAYERS: iteration t computes {L0(t+1) || L1(t)} —
// these are independent given h0(t) (L1 never feeds L0), giving 8
// independent cell chains per scheduling window instead of 4 (r17 lesson:
// latency-bound, TLP axis exhausted; ILP is the remaining lever).
// Virtual-K: lane (q,sl) owns C/D rows 4q..4q+3 of sample sl.
//   layer0 K: e<4 -> h0[4q+e]; e==4,5 -> x[2q],x[2q+1]; e>=6 -> 0
//   layer1 K: e<4 -> h0[4q+e]; e>=4 -> h1[4q+e-4]
//   FC     K: e<4 -> h1[4q+e]; else 0
__global__
__attribute__((amdgpu_flat_work_group_size(256,256)))
__attribute__((amdgpu_waves_per_eu(1,8)))
void lstm_mfma_kernel(const float* __restrict__ in,
                      const float* __restrict__ Wih0, const float* __restrict__ Whh0,
                      const float* __restrict__ bih0, const float* __restrict__ bhh0,
                      const float* __restrict__ Wih1, const float* __restrict__ Whh1,
                      const float* __restrict__ bih1, const float* __restrict__ bhh1,
                      const float* __restrict__ Wfc,  const float* __restrict__ bfc,
                      float* __restrict__ out, int B)
{
    const int lane = threadIdx.x & 63;
    const int wid  = threadIdx.x >> 6;
    const int q  = lane >> 4;       // k-group / row-group
    const int sl = lane & 15;       // sample slot (MFMA col)
    const long s0 = (long)(blockIdx.x*4 + wid)*64;

    // ---- weight A-frags (fp16 RTN, VGPR-resident), exp-scale folded ----
    f16x8 a0[4], a1[4];
    f32x4 bias0[4], bias1[4];
    sfor<0,4>([&](auto MT){ constexpr int mt = MT.value;
        constexpr float SC = (mt==2) ? (2.f*LOG2E) : (-LOG2E);
        const int gr = 16*mt + sl;                 // gate row (A row = sl)
        sfor<0,8>([&](auto E){ constexpr int e = E.value;
            float w0;
            if constexpr (e < 4)      w0 = Whh0[gr*16 + 4*q + e];
            else if constexpr (e < 6) w0 = Wih0[gr*8 + 2*q + (e-4)];
            else                      w0 = 0.f;
            a0[mt][e] = (_Float16)(w0 * SC);
            float w1;
            if constexpr (e < 4) w1 = Wih1[gr*16 + 4*q + e];
            else                 w1 = Whh1[gr*16 + 4*q + (e-4)];
            a1[mt][e] = (_Float16)(w1 * SC);
        });
        sfor<0,4>([&](auto R){ constexpr int r = R.value;
            const int gb = 16*mt + 4*q + r;        // C/D row = 4q+r
            bias0[mt][r] = (bih0[gb] + bhh0[gb]) * SC;
            bias1[mt][r] = (bih1[gb] + bhh1[gb]) * SC;
        });
    });

    // ---- state x4 groups ----
    unsigned P0h[4]={0,0,0,0}, Q0h[4]={0,0,0,0};
    unsigned P1h[4]={0,0,0,0}, Q1h[4]={0,0,0,0};
    f32x4 c0[4], c1[4];
    sfor<0,4>([&](auto G){ constexpr int g=G.value;
        c0[g] = f32x4{0,0,0,0}; c1[g] = f32x4{0,0,0,0};
    });

    const float* xbase = in + (s0 + sl)*64 + 2*q;

    // ---- pipeline prologue: L0(0); xv <- x(1) ----
    float2 xv[4];
    sfor<0,4>([&](auto G){ constexpr int g=G.value;
        float2 x0 = *(const float2*)(xbase + g*1024);
        xv[g]     = *(const float2*)(xbase + g*1024 + 8);
        f16x8 Bh = mkBh(0u, 0u, pkh(x0.x, x0.y), 0u);
        f32x4 dd[4];
        sfor<0,4>([&](auto MT){ constexpr int mt = MT.value;
            dd[mt] = MFMA16H(a0[mt], Bh, bias0[mt], 0,0,0);
        });
        f32x4 hv = cell_tail(dd, c0[g]);
        P0h[g] = pkh(hv[0],hv[1]);  Q0h[g] = pkh(hv[2],hv[3]);
    });

    // ---- steady state: iteration t does L0(t+1) and L1(t) ----
#pragma unroll 2
    for (int t = 0; t < 7; ++t) {
        const int nxt = (t<=5) ? (t+2)*8 : 0;   // prefetch x(t+2); dummy at t=6
        float2 xn[4];
        sfor<0,4>([&](auto G){ constexpr int g=G.value;
            xn[g] = *(const float2*)(xbase + g*1024 + nxt);
        });

        // -- phase A: L0(t+1), consumes old h0 regs, writes new into nP/nQ --
        unsigned nP0[4], nQ0[4];
        sfor<0,4>([&](auto G){ constexpr int g=G.value;
            f16x8 Bh = mkBh(P0h[g], Q0h[g], pkh(xv[g].x, xv[g].y), 0u);
            f32x4 dd[4];
            sfor<0,4>([&](auto MT){ constexpr int mt = MT.value;
                dd[mt] = MFMA16H(a0[mt], Bh, bias0[mt], 0,0,0);
            });
            f32x4 hv = cell_tail(dd, c0[g]);
            nP0[g] = pkh(hv[0],hv[1]);  nQ0[g] = pkh(hv[2],hv[3]);
        });

        // -- phase B: L1(t), consumes old h0 regs (still live, SSA) --
        sfor<0,4>([&](auto G){ constexpr int g=G.value;
            f16x8 Bh = mkBh(P0h[g], Q0h[g], P1h[g], Q1h[g]);
            f32x4 dd[4];
            sfor<0,4>([&](auto MT){ constexpr int mt = MT.value;
                dd[mt] = MFMA16H(a1[mt], Bh, bias1[mt], 0,0,0);
            });
            f32x4 hv = cell_tail(dd, c1[g]);
            P1h[g] = pkh(hv[0],hv[1]);  Q1h[g] = pkh(hv[2],hv[3]);
        });

        sfor<0,4>([&](auto G){ constexpr int g=G.value;
            P0h[g] = nP0[g]; Q0h[g] = nQ0[g]; xv[g] = xn[g];
        });
    }

    // ---- pipeline epilogue: L1(7) ----
    sfor<0,4>([&](auto G){ constexpr int g=G.value;
        f16x8 Bh = mkBh(P0h[g], Q0h[g], P1h[g], Q1h[g]);
        f32x4 dd[4];
        sfor<0,4>([&](auto MT){ constexpr int mt = MT.value;
            dd[mt] = MFMA16H(a1[mt], Bh, bias1[mt], 0,0,0);
        });
        f32x4 hv = cell_tail(dd, c1[g]);
        P1h[g] = pkh(hv[0],hv[1]);  Q1h[g] = pkh(hv[2],hv[3]);
    });

    // ---- FC: single fp16 MFMA from packed h1, biasf in C ----
    {
        f16x8 af;
        f32x4 biasf;
        sfor<0,8>([&](auto E){ constexpr int e = E.value;
            float wf = 0.f;
            if constexpr (e < 4) { if (sl < 10) wf = Wfc[sl*16 + 4*q + e]; }
            af[e] = (_Float16)wf;
        });
        sfor<0,4>([&](auto R){ constexpr int r = R.value;
            const int gb = 4*q + r;
            biasf[r] = (gb < 10) ? bfc[gb] : 0.f;
        });
        sfor<0,4>([&](auto G){ constexpr int g=G.value;
            f16x8 Bh = mkBh(P1h[g], Q1h[g], 0u, 0u);
            f32x4 d = MFMA16H(af, Bh, biasf, 0,0,0);
            float* orow = out + (s0 + g*16 + sl)*10;
            if (q == 0)      { *(float2*)(orow+0) = float2{d[0],d[1]}; *(float2*)(orow+2) = float2{d[2],d[3]}; }
            else if (q == 1) { *(float2*)(orow+4) = float2{d[0],d[1]}; *(float2*)(orow+6) = float2{d[2],d[3]}; }
            else if (q == 2) { *(float2*)(orow+8) = float2{d[0],d[1]}; }
        });
    }
}

extern "C" void kernel_launch(void* const* d_in, const int* in_sizes, int n_in,
                              void* d_out, int out_size, void* d_ws, size_t ws_size,
                              hipStream_t stream) {
    const float* in   = (const float*)d_in[0];
    const float* Wih0 = (const float*)d_in[1];
    const float* Whh0 = (const float*)d_in[2];
    const float* bih0 = (const float*)d_in[3];
    const float* bhh0 = (const float*)d_in[4];
    const float* Wih1 = (const float*)d_in[5];
    const float* Whh1 = (const float*)d_in[6];
    const float* bih1 = (const float*)d_in[7];
    const float* bhh1 = (const float*)d_in[8];
    const float* Wfc  = (const float*)d_in[9];
    const float* bfc  = (const float*)d_in[10];
    float* out = (float*)d_out;

    int B = in_sizes[0] / 64;           // 262144 samples
    int grid = B / 256;                 // 64 samples/wave * 4 waves/block
    lstm_mfma_kernel<<<grid, 256, 0, stream>>>(in, Wih0, Whh0, bih0, bhh0,
                                               Wih1, Whh1, bih1, bhh1,
                                               Wfc, bfc, out, B);
}

// Round 19
// 84.466 us; speedup vs baseline: 1.1121x; 1.0975x over previous
//
#include <hip/hip_runtime.h>

#define LOG2E 1.44269504088896340736f

typedef _Float16 f16x8  __attribute__((ext_vector_type(8)));
typedef float    f32x4  __attribute__((ext_vector_type(4)));

template <int I> struct IntC { static constexpr int value = I; };
template <int I, int N, typename F>
__device__ __forceinline__ void sfor(F&& f) {
    if constexpr (I < N) { f(IntC<I>{}); sfor<I + 1, N>(f); }
}

__device__ __forceinline__ float fexp2(float x){ return __builtin_amdgcn_exp2f(x); }
__device__ __forceinline__ float frcp(float x){ return __builtin_amdgcn_rcpf(x); }

// fp16 pack: single v_cvt_pkrtz_f16_f32
__device__ __forceinline__ unsigned pkh(float a, float b){
    return __builtin_bit_cast(unsigned, __builtin_amdgcn_cvt_pkrtz(a, b));
}
__device__ __forceinline__ f16x8 mkBh(unsigned d0,unsigned d1,unsigned d2,unsigned d3){
    uint4 u{d0,d1,d2,d3};
    return __builtin_bit_cast(f16x8, u);
}

#define MFMA16H __builtin_amdgcn_mfma_f32_16x16x32_f16

// LSTM cell tail. dd[mt] holds SCALED preacts: i',f',o' = -log2e*pre,
// g' = 2log2e*pre. sigma = 1/(1+exp2(-L*pre)); tanh = (E-1)/(E+1).
// Gates: PAIR-batched rcp (r13-proven; quad-batch serialized the path,
// +7us r15). tanh(c): UNBATCHED — 4 independent rcp. The r13 quad-batch
// here was a ~9-op serial product/unwind chain ON the recurrence critical
// path (hv -> pack -> next MFMA); we're latency-bound with trans-pipe
// headroom, so 3 extra rcps buy ~7 fewer serial ops per step.
__device__ __forceinline__ f32x4 cell_tail(const f32x4 (&dd)[4], f32x4& c){
    f32x4 Ei, Ef, Eg, Eo;
    sfor<0,4>([&](auto R){ constexpr int r=R.value;
        Ei[r] = fexp2(dd[0][r]);
        Ef[r] = fexp2(dd[1][r]);
        Eg[r] = fexp2(dd[2][r]);
        Eo[r] = fexp2(dd[3][r]);
    });
    f32x4 ov, cn;
    sfor<0,4>([&](auto R){ constexpr int r=R.value;
        float Ai = 1.f + Ei[r], Af = 1.f + Ef[r];
        float Ag = 1.f + Eg[r], Ao = 1.f + Eo[r];
        float p  = Ai*Af;  float rp = frcp(p);
        float iv = Af*rp;                 // sigma(i)
        float fv = Ai*rp;                 // sigma(f)
        float q2 = Ag*Ao;  float rq = frcp(q2);
        float gr = Ao*rq;                 // 1/Ag
        ov[r]    = Ag*rq;                 // sigma(o)
        float gv = (Eg[r]-1.f)*gr;        // tanh(g)
        cn[r] = fv*c[r] + iv*gv;
    });
    c = cn;
    f32x4 hv;
    sfor<0,4>([&](auto R){ constexpr int r=R.value;
        float tc = fexp2(cn[r]*(2.f*LOG2E));
        float Rr = frcp(tc + 1.f);        // independent chain per row
        hv[r] = ov[r]*((tc - 1.f)*Rr);
    });
    return hv;
}

// One wave = 64 samples (4 groups of 16), ZERO LDS, all-fp16 MFMA.
// r13 structure exactly (best measured: 81.7us) + pkrtz pack + fp16 FC.
// Virtual-K: lane (q,sl) owns C/D rows 4q..4q+3 of sample sl; B element
// k=8q+e is that lane's own packed registers.
//   layer0 K: e<4 -> h0[4q+e]; e==4,5 -> x[2q],x[2q+1]; e>=6 -> 0
//   layer1 K: e<4 -> h0[4q+e]; e>=4 -> h1[4q+e-4]
//   FC     K: e<4 -> h1[4q+e]; else 0
__global__
__attribute__((amdgpu_flat_work_group_size(256,256)))
__attribute__((amdgpu_waves_per_eu(1,8)))
void lstm_mfma_kernel(const float* __restrict__ in,
                      const float* __restrict__ Wih0, const float* __restrict__ Whh0,
                      const float* __restrict__ bih0, const float* __restrict__ bhh0,
                      const float* __restrict__ Wih1, const float* __restrict__ Whh1,
                      const float* __restrict__ bih1, const float* __restrict__ bhh1,
                      const float* __restrict__ Wfc,  const float* __restrict__ bfc,
                      float* __restrict__ out, int B)
{
    const int lane = threadIdx.x & 63;
    const int wid  = threadIdx.x >> 6;
    const int q  = lane >> 4;       // k-group / row-group
    const int sl = lane & 15;       // sample slot (MFMA col)
    const long s0 = (long)(blockIdx.x*4 + wid)*64;

    // ---- weight A-frags (fp16 RTN, VGPR-resident), exp-scale folded ----
    f16x8 a0[4], a1[4];
    f32x4 bias0[4], bias1[4];
    sfor<0,4>([&](auto MT){ constexpr int mt = MT.value;
        constexpr float SC = (mt==2) ? (2.f*LOG2E) : (-LOG2E);
        const int gr = 16*mt + sl;                 // gate row (A row = sl)
        sfor<0,8>([&](auto E){ constexpr int e = E.value;
            float w0;
            if constexpr (e < 4)      w0 = Whh0[gr*16 + 4*q + e];
            else if constexpr (e < 6) w0 = Wih0[gr*8 + 2*q + (e-4)];
            else                      w0 = 0.f;
            a0[mt][e] = (_Float16)(w0 * SC);
            float w1;
            if constexpr (e < 4) w1 = Wih1[gr*16 + 4*q + e];
            else                 w1 = Whh1[gr*16 + 4*q + (e-4)];
            a1[mt][e] = (_Float16)(w1 * SC);
        });
        sfor<0,4>([&](auto R){ constexpr int r = R.value;
            const int gb = 16*mt + 4*q + r;        // C/D row = 4q+r
            bias0[mt][r] = (bih0[gb] + bhh0[gb]) * SC;
            bias1[mt][r] = (bih1[gb] + bhh1[gb]) * SC;
        });
    });

    // ---- state x4 groups: fp16-packed h + f32 cell, all lane-local ----
    unsigned P0h[4]={0,0,0,0}, Q0h[4]={0,0,0,0};
    unsigned P1h[4]={0,0,0,0}, Q1h[4]={0,0,0,0};
    f32x4 c0[4], c1[4];
    sfor<0,4>([&](auto G){ constexpr int g=G.value;
        c0[g] = f32x4{0,0,0,0}; c1[g] = f32x4{0,0,0,0};
    });

    // ---- x stream: EVERY lane loads float2 = x_t[sample][2q..2q+1] ----
    const float* xbase = in + (s0 + sl)*64 + 2*q;
    float2 xv[4];
    sfor<0,4>([&](auto G){ constexpr int g=G.value;
        xv[g] = *(const float2*)(xbase + g*1024);
    });

#pragma unroll 2
    for (int t = 0; t < 8; ++t) {
        // prefetch next step's x (t==7: reload t=0, discarded — in bounds)
        const int nxt = (t==7) ? 0 : (t+1)*8;
        float2 xn[4];
        sfor<0,4>([&](auto G){ constexpr int g=G.value;
            xn[g] = *(const float2*)(xbase + g*1024 + nxt);
        });

        // ================= layer 0 (4 groups: independent chains) ==========
        sfor<0,4>([&](auto G){ constexpr int g=G.value;
            const unsigned xh = pkh(xv[g].x, xv[g].y);
            f16x8 Bh = mkBh(P0h[g], Q0h[g], xh, 0u);
            f32x4 dd[4];
            sfor<0,4>([&](auto MT){ constexpr int mt = MT.value;
                dd[mt] = MFMA16H(a0[mt], Bh, bias0[mt], 0,0,0);
            });
            f32x4 hv = cell_tail(dd, c0[g]);
            P0h[g] = pkh(hv[0],hv[1]);  Q0h[g] = pkh(hv[2],hv[3]);
        });

        // ================= layer 1 (4 groups) ==============================
        sfor<0,4>([&](auto G){ constexpr int g=G.value;
            f16x8 Bh = mkBh(P0h[g], Q0h[g], P1h[g], Q1h[g]);
            f32x4 dd[4];
            sfor<0,4>([&](auto MT){ constexpr int mt = MT.value;
                dd[mt] = MFMA16H(a1[mt], Bh, bias1[mt], 0,0,0);
            });
            f32x4 hv = cell_tail(dd, c1[g]);
            P1h[g] = pkh(hv[0],hv[1]);  Q1h[g] = pkh(hv[2],hv[3]);
        });

        sfor<0,4>([&](auto G){ constexpr int g=G.value; xv[g] = xn[g]; });
    }

    // ================= FC: single fp16 MFMA from packed h1, biasf in C =====
    {
        f16x8 af;
        f32x4 biasf;
        sfor<0,8>([&](auto E){ constexpr int e = E.value;
            float wf = 0.f;
            if constexpr (e < 4) { if (sl < 10) wf = Wfc[sl*16 + 4*q + e]; }
            af[e] = (_Float16)wf;
        });
        sfor<0,4>([&](auto R){ constexpr int r = R.value;
            const int gb = 4*q + r;
            biasf[r] = (gb < 10) ? bfc[gb] : 0.f;
        });
        sfor<0,4>([&](auto G){ constexpr int g=G.value;
            f16x8 Bh = mkBh(P1h[g], Q1h[g], 0u, 0u);
            f32x4 d = MFMA16H(af, Bh, biasf, 0,0,0);
            float* orow = out + (s0 + g*16 + sl)*10;
            if (q == 0)      { *(float2*)(orow+0) = float2{d[0],d[1]}; *(float2*)(orow+2) = float2{d[2],d[3]}; }
            else if (q == 1) { *(float2*)(orow+4) = float2{d[0],d[1]}; *(float2*)(orow+6) = float2{d[2],d[3]}; }
            else if (q == 2) { *(float2*)(orow+8) = float2{d[0],d[1]}; }
        });
    }
}

extern "C" void kernel_launch(void* const* d_in, const int* in_sizes, int n_in,
                              void* d_out, int out_size, void* d_ws, size_t ws_size,
                              hipStream_t stream) {
    const float* in   = (const float*)d_in[0];
    const float* Wih0 = (const float*)d_in[1];
    const float* Whh0 = (const float*)d_in[2];
    const float* bih0 = (const float*)d_in[3];
    const float* bhh0 = (const float*)d_in[4];
    const float* Wih1 = (const float*)d_in[5];
    const float* Whh1 = (const float*)d_in[6];
    const float* bih1 = (const float*)d_in[7];
    const float* bhh1 = (const float*)d_in[8];
    const float* Wfc  = (const float*)d_in[9];
    const float* bfc  = (const float*)d_in[10];
    float* out = (float*)d_out;

    int B = in_sizes[0] / 64;           // 262144 samples
    int grid = B / 256;                 // 64 samples/wave * 4 waves/block
    lstm_mfma_kernel<<<grid, 256, 0, stream>>>(in, Wih0, Whh0, bih0, bhh0,
                                               Wih1, Whh1, bih1, bhh1,
                                               Wfc, bfc, out, B);
}

// Round 20
// 81.147 us; speedup vs baseline: 1.1576x; 1.0409x over previous
//
#include <hip/hip_runtime.h>

#define LOG2E 1.44269504088896340736f

typedef short    bf16x8 __attribute__((ext_vector_type(8)));
typedef _Float16 f16x8  __attribute__((ext_vector_type(8)));
typedef float    f32x4  __attribute__((ext_vector_type(4)));

template <int I> struct IntC { static constexpr int value = I; };
template <int I, int N, typename F>
__device__ __forceinline__ void sfor(F&& f) {
    if constexpr (I < N) { f(IntC<I>{}); sfor<I + 1, N>(f); }
}

__device__ __forceinline__ float fexp2(float x){ return __builtin_amdgcn_exp2f(x); }
__device__ __forceinline__ float frcp(float x){ return __builtin_amdgcn_rcpf(x); }

__device__ __forceinline__ float hi_part(float x){
    return __uint_as_float(__float_as_uint(x) & 0xFFFF0000u);
}
// bf16 pack (FC epilogue only)
__device__ __forceinline__ unsigned pk2(float a, float b){
    return __builtin_amdgcn_perm(__float_as_uint(b), __float_as_uint(a), 0x07060302u);
}
__device__ __forceinline__ unsigned pk2lo(float a, float b){
    return pk2(a - hi_part(a), b - hi_part(b));
}
// fp16 RTN pack: 2x v_cvt_f16_f32 (round-nearest) + pack
__device__ __forceinline__ unsigned pkh(float a, float b){
    unsigned short ua = __builtin_bit_cast(unsigned short, (_Float16)a);
    unsigned short ub = __builtin_bit_cast(unsigned short, (_Float16)b);
    return (unsigned)ua | ((unsigned)ub << 16);
}
__device__ __forceinline__ bf16x8 mkB(unsigned d0,unsigned d1,unsigned d2,unsigned d3){
    uint4 u{d0,d1,d2,d3};
    return __builtin_bit_cast(bf16x8, u);
}
__device__ __forceinline__ f16x8 mkBh(unsigned d0,unsigned d1,unsigned d2,unsigned d3){
    uint4 u{d0,d1,d2,d3};
    return __builtin_bit_cast(f16x8, u);
}

#define MFMA16  __builtin_amdgcn_mfma_f32_16x16x32_bf16
#define MFMA16H __builtin_amdgcn_mfma_f32_16x16x32_f16

// LSTM cell tail. dd[mt] holds SCALED preacts: i',f',o' = -log2e*pre,
// g' = 2log2e*pre (scales folded into weights+biases).
// sigma = 1/(1+exp2(-L*pre)); tanh = (E-1)/(E+1). rcp pair/quad-batched.
__device__ __forceinline__ f32x4 cell_tail(const f32x4 (&dd)[4], f32x4& c){
    f32x4 Ei, Ef, Eg, Eo;
    sfor<0,4>([&](auto R){ constexpr int r=R.value;
        Ei[r] = fexp2(dd[0][r]);
        Ef[r] = fexp2(dd[1][r]);
        Eg[r] = fexp2(dd[2][r]);
        Eo[r] = fexp2(dd[3][r]);
    });
    f32x4 ov, cn;
    sfor<0,4>([&](auto R){ constexpr int r=R.value;
        float Ai = 1.f + Ei[r], Af = 1.f + Ef[r];
        float Ag = 1.f + Eg[r], Ao = 1.f + Eo[r];
        float p  = Ai*Af;  float rp = frcp(p);
        float iv = Af*rp;                 // sigma(i)
        float fv = Ai*rp;                 // sigma(f)
        float q2 = Ag*Ao;  float rq = frcp(q2);
        float gr = Ao*rq;                 // 1/Ag
        ov[r]    = Ag*rq;                 // sigma(o)
        float gv = (Eg[r]-1.f)*gr;        // tanh(g)
        cn[r] = fv*c[r] + iv*gv;
    });
    c = cn;
    f32x4 tc;
    sfor<0,4>([&](auto R){ constexpr int r=R.value;
        tc[r] = fexp2(cn[r]*(2.f*LOG2E));
    });
    float B0=tc[0]+1.f, B1=tc[1]+1.f, B2=tc[2]+1.f, B3=tc[3]+1.f;
    float P2=B0*B1, P3=P2*B2, P4=P3*B3;
    float r4=frcp(P4);
    float R3=P3*r4;
    float r3=B3*r4;
    float R2=P2*r3;
    float r2=B2*r3;
    float R1=B0*r2;
    float R0=B1*r2;
    f32x4 hv;
    hv[0] = ov[0]*((tc[0]-1.f)*R0);
    hv[1] = ov[1]*((tc[1]-1.f)*R1);
    hv[2] = ov[2]*((tc[2]-1.f)*R2);
    hv[3] = ov[3]*((tc[3]-1.f)*R3);
    return hv;
}

// One wave = 64 samples (4 groups of 16), ZERO LDS. Virtual-K permutation:
// lane (q,sl) owns C/D rows 4q..4q+3 of sample sl; B element k=8q+e is that
// lane's own packed registers. SINGLE fp16 MFMA per gate tile. FC epilogue
// bf16 hi/lo 3-MFMA fed from f32 last-h (undamped path to output).
//   layer0 K: e<4 -> h0[4q+e]; e==4,5 -> x[2q],x[2q+1]; e>=6 -> 0
//   layer1 K: e<4 -> h0[4q+e]; e>=4 -> h1[4q+e-4]
//   FC     K: e<4 -> h1[4q+e]; e>=4 -> 0
__global__
__attribute__((amdgpu_flat_work_group_size(256,256)))
__attribute__((amdgpu_waves_per_eu(1,8)))
void lstm_mfma_kernel(const float* __restrict__ in,
                      const float* __restrict__ Wih0, const float* __restrict__ Whh0,
                      const float* __restrict__ bih0, const float* __restrict__ bhh0,
                      const float* __restrict__ Wih1, const float* __restrict__ Whh1,
                      const float* __restrict__ bih1, const float* __restrict__ bhh1,
                      const float* __restrict__ Wfc,  const float* __restrict__ bfc,
                      float* __restrict__ out, int B)
{
    const int lane = threadIdx.x & 63;
    const int wid  = threadIdx.x >> 6;
    const int q  = lane >> 4;       // k-group / row-group
    const int sl = lane & 15;       // sample slot (MFMA col)
    const long s0 = (long)(blockIdx.x*4 + wid)*64;

    // ---- weight A-frags (fp16 RTN, VGPR-resident), virtual-K layout,
    //      exp-scale folded per gate: mt==2 (g): +2*log2e, else -log2e ----
    f16x8 a0[4], a1[4];
    f32x4 bias0[4], bias1[4];
    sfor<0,4>([&](auto MT){ constexpr int mt = MT.value;
        constexpr float SC = (mt==2) ? (2.f*LOG2E) : (-LOG2E);
        const int gr = 16*mt + sl;                 // gate row (A row = sl)
        sfor<0,8>([&](auto E){ constexpr int e = E.value;
            float w0;
            if constexpr (e < 4)      w0 = Whh0[gr*16 + 4*q + e];
            else if constexpr (e < 6) w0 = Wih0[gr*8 + 2*q + (e-4)];
            else                      w0 = 0.f;
            a0[mt][e] = (_Float16)(w0 * SC);
            float w1;
            if constexpr (e < 4) w1 = Wih1[gr*16 + 4*q + e];
            else                 w1 = Whh1[gr*16 + 4*q + (e-4)];
            a1[mt][e] = (_Float16)(w1 * SC);
        });
        sfor<0,4>([&](auto R){ constexpr int r = R.value;
            const int gb = 16*mt + 4*q + r;        // C/D row = 4q+r
            bias0[mt][r] = (bih0[gb] + bhh0[gb]) * SC;
            bias1[mt][r] = (bih1[gb] + bhh1[gb]) * SC;
        });
    });

    // ---- state x4 groups: fp16-packed h + f32 cell, all lane-local ----
    unsigned P0h[4]={0,0,0,0}, Q0h[4]={0,0,0,0};
    unsigned P1h[4]={0,0,0,0}, Q1h[4]={0,0,0,0};
    f32x4 c0[4], c1[4], hl1[4];
    sfor<0,4>([&](auto G){ constexpr int g=G.value;
        c0[g] = f32x4{0,0,0,0}; c1[g] = f32x4{0,0,0,0};
        hl1[g] = f32x4{0,0,0,0};
    });

    // ---- x stream: EVERY lane loads float2 = x_t[sample][2q..2q+1] ----
    const float* xbase = in + (s0 + sl)*64 + 2*q;
    float2 xv[4];
    sfor<0,4>([&](auto G){ constexpr int g=G.value;
        xv[g] = *(const float2*)(xbase + g*1024);
    });

#pragma unroll 2
    for (int t = 0; t < 8; ++t) {
        // prefetch next step's x (t==7: reload t=0, discarded — in bounds)
        const int nxt = (t==7) ? 0 : (t+1)*8;
        float2 xn[4];
        sfor<0,4>([&](auto G){ constexpr int g=G.value;
            xn[g] = *(const float2*)(xbase + g*1024 + nxt);
        });

        // ================= layer 0 (4 groups: independent chains) ==========
        sfor<0,4>([&](auto G){ constexpr int g=G.value;
            const unsigned xh = pkh(xv[g].x, xv[g].y);
            f16x8 Bh = mkBh(P0h[g], Q0h[g], xh, 0u);
            f32x4 dd[4];
            sfor<0,4>([&](auto MT){ constexpr int mt = MT.value;
                dd[mt] = MFMA16H(a0[mt], Bh, bias0[mt], 0,0,0);
            });
            f32x4 hv = cell_tail(dd, c0[g]);
            P0h[g] = pkh(hv[0],hv[1]);  Q0h[g] = pkh(hv[2],hv[3]);
        });

        // ================= layer 1 (4 groups) ==============================
        sfor<0,4>([&](auto G){ constexpr int g=G.value;
            f16x8 Bh = mkBh(P0h[g], Q0h[g], P1h[g], Q1h[g]);
            f32x4 dd[4];
            sfor<0,4>([&](auto MT){ constexpr int mt = MT.value;
                dd[mt] = MFMA16H(a1[mt], Bh, bias1[mt], 0,0,0);
            });
            f32x4 hv = cell_tail(dd, c1[g]);
            hl1[g] = hv;                           // f32 last-h for FC
            P1h[g] = pkh(hv[0],hv[1]);  Q1h[g] = pkh(hv[2],hv[3]);
        });

        sfor<0,4>([&](auto G){ constexpr int g=G.value; xv[g] = xn[g]; });
    }

    // ================= FC (bf16 hi/lo 3-MFMA, f32 last-h, UNSCALED) ========
    {
        bf16x8 afh, afl;
        f32x4 biasf;
        sfor<0,8>([&](auto E){ constexpr int e = E.value;
            float wf = 0.f;
            if constexpr (e < 4) { if (sl < 10) wf = Wfc[sl*16 + 4*q + e]; }
            afh[e] = (short)(__float_as_uint(wf)>>16);
            afl[e] = (short)(__float_as_uint(wf - hi_part(wf))>>16);
        });
        sfor<0,4>([&](auto R){ constexpr int r = R.value;
            const int gb = 4*q + r;
            biasf[r] = (gb < 10) ? bfc[gb] : 0.f;
        });
        sfor<0,4>([&](auto G){ constexpr int g=G.value;
            const unsigned Fh0 = pk2(hl1[g][0], hl1[g][1]);
            const unsigned Fh1 = pk2(hl1[g][2], hl1[g][3]);
            const unsigned Fl0 = pk2lo(hl1[g][0], hl1[g][1]);
            const unsigned Fl1 = pk2lo(hl1[g][2], hl1[g][3]);
            bf16x8 Bh = mkB(Fh0, Fh1, 0u, 0u);
            bf16x8 Bl = mkB(Fl0, Fl1, 0u, 0u);
            f32x4 d = MFMA16(afl, Bh, biasf, 0,0,0);
            d = MFMA16(afh, Bl, d, 0,0,0);
            d = MFMA16(afh, Bh, d, 0,0,0);
            float* orow = out + (s0 + g*16 + sl)*10;
            if (q == 0)      { *(float2*)(orow+0) = float2{d[0],d[1]}; *(float2*)(orow+2) = float2{d[2],d[3]}; }
            else if (q == 1) { *(float2*)(orow+4) = float2{d[0],d[1]}; *(float2*)(orow+6) = float2{d[2],d[3]}; }
            else if (q == 2) { *(float2*)(orow+8) = float2{d[0],d[1]}; }
        });
    }
}

extern "C" void kernel_launch(void* const* d_in, const int* in_sizes, int n_in,
                              void* d_out, int out_size, void* d_ws, size_t ws_size,
                              hipStream_t stream) {
    const float* in   = (const float*)d_in[0];
    const float* Wih0 = (const float*)d_in[1];
    const float* Whh0 = (const float*)d_in[2];
    const float* bih0 = (const float*)d_in[3];
    const float* bhh0 = (const float*)d_in[4];
    const float* Wih1 = (const float*)d_in[5];
    const float* Whh1 = (const float*)d_in[6];
    const float* bih1 = (const float*)d_in[7];
    const float* bhh1 = (const float*)d_in[8];
    const float* Wfc  = (const float*)d_in[9];
    const float* bfc  = (const float*)d_in[10];
    float* out = (float*)d_out;

    int B = in_sizes[0] / 64;           // 262144 samples
    int grid = B / 256;                 // 64 samples/wave * 4 waves/block
    lstm_mfma_kernel<<<grid, 256, 0, stream>>>(in, Wih0, Whh0, bih0, bhh0,
                                               Wih1, Whh1, bih1, bhh1,
                                               Wfc, bfc, out, B);
}